// Round 3
// baseline (3047.325 us; speedup 1.0000x reference)
//
#include <hip/hip_runtime.h>

// GCRN (AGCRN-style) on gfx950. Inputs/outputs fp32 (per reference); internal
// compute bf16 MFMA (compare threshold is bf16-relaxed).
// A = softmax(relu(E E^T)); AA = [A; 2A^2] stacked (T2 = 2A^2 - I folded into
// weights: W0' = W0 - W2). Per GRU cell: S = AA @ h (bf16 MFMA), then fused
// gate/update GEMMs (K=192 over [h, A h, 2A^2 h]) with rank-1 x/go/y corrections
// in the epilogue. h state fp32; MFMA operands bf16, K-contiguous.

typedef __attribute__((ext_vector_type(8))) short bf16x8;
typedef __attribute__((ext_vector_type(4))) float f32x4;
typedef __attribute__((ext_vector_type(4))) unsigned short u16x4;

__device__ __forceinline__ float b2f(unsigned short u) {
    union { unsigned int i; float f; } v; v.i = ((unsigned int)u) << 16; return v.f;
}
__device__ __forceinline__ unsigned short f2b(float f) {
    union { float f; unsigned int i; } v; v.f = f;
    unsigned int r = v.i + 0x7FFFu + ((v.i >> 16) & 1u);
    return (unsigned short)(r >> 16);
}

// ---------------------------------------------------------------------------
// Generic bf16 GEMM: C[m,n] = scale * sum_k P[m,k] * QT[n,k].  (both K-contig)
// grid.x = N/128, grid.y = M/128, 256 threads.
// ---------------------------------------------------------------------------
__global__ __launch_bounds__(256) void gemm_bt(
    const unsigned short* __restrict__ P, int lda,
    const unsigned short* __restrict__ QT, int ldb,
    unsigned short* __restrict__ C, int ldc,
    int K, float scale)
{
    __shared__ __align__(16) unsigned short As[128 * 32];
    __shared__ __align__(16) unsigned short Bs[128 * 32];
    const int tid = threadIdx.x;
    const int m0 = blockIdx.y << 7, n0 = blockIdx.x << 7;
    const int w = tid >> 6, l = tid & 63;
    const int wm = (w >> 1) << 6, wn = (w & 1) << 6;
    const int lr = l & 15, lq = l >> 4;
    const int arow = tid >> 2, ak = (tid & 3) << 3;
    f32x4 acc[4][4] = {};

    for (int k0 = 0; k0 < K; k0 += 32) {
        bf16x8 ta[2], tb[2];
#pragma unroll
        for (int p = 0; p < 2; ++p)
            ta[p] = *(const bf16x8*)(P + (size_t)(m0 + arow + (p << 6)) * lda + k0 + ak);
#pragma unroll
        for (int p = 0; p < 2; ++p)
            tb[p] = *(const bf16x8*)(QT + (size_t)(n0 + arow + (p << 6)) * ldb + k0 + ak);
#pragma unroll
        for (int p = 0; p < 2; ++p) {
            *(bf16x8*)&As[((arow + (p << 6)) << 5) + ak] = ta[p];
            *(bf16x8*)&Bs[((arow + (p << 6)) << 5) + ak] = tb[p];
        }
        __syncthreads();
        bf16x8 a[4], b[4];
#pragma unroll
        for (int i = 0; i < 4; ++i)
            a[i] = *(const bf16x8*)&As[((wm + (i << 4) + lr) << 5) + (lq << 3)];
#pragma unroll
        for (int j = 0; j < 4; ++j)
            b[j] = *(const bf16x8*)&Bs[((wn + (j << 4) + lr) << 5) + (lq << 3)];
#pragma unroll
        for (int i = 0; i < 4; ++i)
#pragma unroll
            for (int j = 0; j < 4; ++j)
                acc[i][j] = __builtin_amdgcn_mfma_f32_16x16x32_bf16(a[i], b[j], acc[i][j], 0, 0, 0);
        __syncthreads();
    }
#pragma unroll
    for (int i = 0; i < 4; ++i)
#pragma unroll
        for (int j = 0; j < 4; ++j)
#pragma unroll
            for (int r = 0; r < 4; ++r) {
                const int m = m0 + wm + (i << 4) + (lq << 2) + r;
                const int n = n0 + wn + (j << 4) + lr;
                C[(size_t)m * ldc + n] = f2b(acc[i][j][r] * scale);
            }
}

// ---------------------------------------------------------------------------
// Fused gate GEMM: zr = sigmoid( [h | A h | 2A^2 h] @ W' + bias + corr )
// grid 512 (b in [0,64), node-tile in [0,8)), N=128, K=192.
// z (cols 0..63) -> Zb = z*h (b,n,c) + ZhT (b,c,n);  r (cols 64..127) -> R fp32.
// ---------------------------------------------------------------------------
__global__ __launch_bounds__(256) void gru_gate(
    const unsigned short* __restrict__ Hb, const unsigned short* __restrict__ S, int ldS,
    const unsigned short* __restrict__ WT, const float* __restrict__ bias,
    const float* __restrict__ wx, const float* __restrict__ xin, int t,
    const unsigned short* __restrict__ XSgT, int xsrow, const unsigned short* __restrict__ Go,
    const float* __restrict__ H32,
    unsigned short* __restrict__ Zb, unsigned short* __restrict__ ZhT, float* __restrict__ R,
    int dec)
{
    __shared__ __align__(16) unsigned short As[128 * 32];
    __shared__ __align__(16) unsigned short Bs[128 * 32];
    const int tid = threadIdx.x;
    const int rb = blockIdx.x;
    const int b = rb >> 3, n0 = (rb & 7) << 7;
    const int w = tid >> 6, l = tid & 63;
    const int wm = (w >> 1) << 6, wn = (w & 1) << 6;
    const int lr = l & 15, lq = l >> 4;
    const int arow = tid >> 2, ak = (tid & 3) << 3;
    f32x4 acc[4][4] = {};

    const unsigned short* sbase[3];
    size_t sstride[3];
    sbase[0] = Hb + ((size_t)(b << 10) + n0) * 64;        sstride[0] = 64;
    sbase[1] = S + (size_t)n0 * ldS + (b << 6);           sstride[1] = (size_t)ldS;
    sbase[2] = S + (size_t)(1024 + n0) * ldS + (b << 6);  sstride[2] = (size_t)ldS;

    for (int kk0 = 0; kk0 < 192; kk0 += 32) {
        const int seg = kk0 >> 6, so = kk0 & 63;
        bf16x8 ta[2], tb[2];
#pragma unroll
        for (int p = 0; p < 2; ++p)
            ta[p] = *(const bf16x8*)(sbase[seg] + (size_t)(arow + (p << 6)) * sstride[seg] + so + ak);
#pragma unroll
        for (int p = 0; p < 2; ++p)
            tb[p] = *(const bf16x8*)(WT + (size_t)(arow + (p << 6)) * 192 + kk0 + ak);
#pragma unroll
        for (int p = 0; p < 2; ++p) {
            *(bf16x8*)&As[((arow + (p << 6)) << 5) + ak] = ta[p];
            *(bf16x8*)&Bs[((arow + (p << 6)) << 5) + ak] = tb[p];
        }
        __syncthreads();
        bf16x8 a[4], bb[4];
#pragma unroll
        for (int i = 0; i < 4; ++i)
            a[i] = *(const bf16x8*)&As[((wm + (i << 4) + lr) << 5) + (lq << 3)];
#pragma unroll
        for (int j = 0; j < 4; ++j)
            bb[j] = *(const bf16x8*)&Bs[((wn + (j << 4) + lr) << 5) + (lq << 3)];
#pragma unroll
        for (int i = 0; i < 4; ++i)
#pragma unroll
            for (int j = 0; j < 4; ++j)
                acc[i][j] = __builtin_amdgcn_mfma_f32_16x16x32_bf16(a[i], bb[j], acc[i][j], 0, 0, 0);
        __syncthreads();
    }

#pragma unroll
    for (int i = 0; i < 4; ++i) {
        const int node_base = n0 + wm + (i << 4) + (lq << 2);
        float c0[4], c1[4], c2[4], c3[4], c4[4], c5[4];
        for (int r = 0; r < 4; ++r) {
            const int node = node_base + r;
            if (!dec) {
                c0[r] = xin[((b * 12 + t) << 10) + node];
                c1[r] = b2f(XSgT[(size_t)(xsrow + t * 64 + b) * 2048 + node]);
                c2[r] = b2f(XSgT[(size_t)(xsrow + t * 64 + b) * 2048 + 1024 + node]);
                c3[r] = c4[r] = c5[r] = 0.f;
            } else {
                c0[r] = b2f(Go[(b << 10) + node]);
                c1[r] = xin[((b * 12 + t) << 10) + node];
                c2[r] = b2f(S[(size_t)node * ldS + 4096 + b]);
                c3[r] = b2f(XSgT[(size_t)(xsrow + t * 64 + b) * 2048 + node]);
                c4[r] = b2f(S[(size_t)(1024 + node) * ldS + 4096 + b]);
                c5[r] = b2f(XSgT[(size_t)(xsrow + t * 64 + b) * 2048 + 1024 + node]);
            }
        }
#pragma unroll
        for (int j = 0; j < 4; ++j) {
            const int jc = wn + (j << 4) + lr;
            const float bj = bias[jc];
            const float w0 = wx[jc], w1 = wx[128 + jc], w2 = wx[256 + jc];
            float w3 = 0.f, w4 = 0.f, w5 = 0.f;
            if (dec) { w3 = wx[384 + jc]; w4 = wx[512 + jc]; w5 = wx[640 + jc]; }
            if (jc < 64) {
                u16x4 pack;
                for (int r = 0; r < 4; ++r) {
                    float v = acc[i][j][r] + bj + c0[r] * w0 + c1[r] * w1 + c2[r] * w2
                              + c3[r] * w3 + c4[r] * w4 + c5[r] * w5;
                    float g = 1.f / (1.f + __expf(-v));
                    const int node = node_base + r;
                    const size_t idx = ((size_t)(b << 10) + node) * 64 + jc;
                    float zh = g * H32[idx];
                    unsigned short zb = f2b(zh);
                    Zb[idx] = zb;
                    pack[r] = zb;
                }
                *(u16x4*)&ZhT[(size_t)((b << 6) + jc) * 1024 + node_base] = pack;
            } else {
                for (int r = 0; r < 4; ++r) {
                    float v = acc[i][j][r] + bj + c0[r] * w0 + c1[r] * w1 + c2[r] * w2
                              + c3[r] * w3 + c4[r] * w4 + c5[r] * w5;
                    float g = 1.f / (1.f + __expf(-v));
                    const int node = node_base + r;
                    R[((size_t)(b << 10) + node) * 64 + (jc - 64)] = g;
                }
            }
        }
    }
}

// ---------------------------------------------------------------------------
// Fused update GEMM: hc = tanh([zh | A zh | 2A^2 zh] @ Wu' + bias + corr);
// h' = r*h + (1-r)*hc.  N=64.  Writes H32 (fp32), Hb (b,n,c), XhT (b,c,n).
// ---------------------------------------------------------------------------
__global__ __launch_bounds__(256) void gru_update(
    const unsigned short* __restrict__ Zb, const unsigned short* __restrict__ S, int ldS,
    const unsigned short* __restrict__ WT, const float* __restrict__ bias,
    const float* __restrict__ wx, const float* __restrict__ xin, int t,
    const unsigned short* __restrict__ XSgT, int xsrow, const unsigned short* __restrict__ Go,
    const float* __restrict__ Rg,
    float* __restrict__ H32, unsigned short* __restrict__ Hb, unsigned short* __restrict__ XhT,
    int dec)
{
    __shared__ __align__(16) unsigned short As[128 * 32];
    __shared__ __align__(16) unsigned short Bs[64 * 32];
    const int tid = threadIdx.x;
    const int rb = blockIdx.x;
    const int b = rb >> 3, n0 = (rb & 7) << 7;
    const int w = tid >> 6, l = tid & 63;
    const int wm = w << 5;
    const int lr = l & 15, lq = l >> 4;
    const int arow = tid >> 2, ak = (tid & 3) << 3;
    f32x4 acc[2][4] = {};

    const unsigned short* sbase[3];
    size_t sstride[3];
    sbase[0] = Zb + ((size_t)(b << 10) + n0) * 64;        sstride[0] = 64;
    sbase[1] = S + (size_t)n0 * ldS + (b << 6);           sstride[1] = (size_t)ldS;
    sbase[2] = S + (size_t)(1024 + n0) * ldS + (b << 6);  sstride[2] = (size_t)ldS;

    for (int kk0 = 0; kk0 < 192; kk0 += 32) {
        const int seg = kk0 >> 6, so = kk0 & 63;
        bf16x8 ta[2], tb;
#pragma unroll
        for (int p = 0; p < 2; ++p)
            ta[p] = *(const bf16x8*)(sbase[seg] + (size_t)(arow + (p << 6)) * sstride[seg] + so + ak);
        tb = *(const bf16x8*)(WT + (size_t)arow * 192 + kk0 + ak);
#pragma unroll
        for (int p = 0; p < 2; ++p)
            *(bf16x8*)&As[((arow + (p << 6)) << 5) + ak] = ta[p];
        if (arow < 64) *(bf16x8*)&Bs[(arow << 5) + ak] = tb;
        __syncthreads();
        bf16x8 a[2], bb[4];
#pragma unroll
        for (int i = 0; i < 2; ++i)
            a[i] = *(const bf16x8*)&As[((wm + (i << 4) + lr) << 5) + (lq << 3)];
#pragma unroll
        for (int j = 0; j < 4; ++j)
            bb[j] = *(const bf16x8*)&Bs[(((j << 4) + lr) << 5) + (lq << 3)];
#pragma unroll
        for (int i = 0; i < 2; ++i)
#pragma unroll
            for (int j = 0; j < 4; ++j)
                acc[i][j] = __builtin_amdgcn_mfma_f32_16x16x32_bf16(a[i], bb[j], acc[i][j], 0, 0, 0);
        __syncthreads();
    }

#pragma unroll
    for (int i = 0; i < 2; ++i) {
        const int node_base = n0 + wm + (i << 4) + (lq << 2);
        float c0[4], c1[4], c2[4], c3[4], c4[4], c5[4];
        for (int r = 0; r < 4; ++r) {
            const int node = node_base + r;
            if (!dec) {
                c0[r] = xin[((b * 12 + t) << 10) + node];
                c1[r] = b2f(XSgT[(size_t)(xsrow + t * 64 + b) * 2048 + node]);
                c2[r] = b2f(XSgT[(size_t)(xsrow + t * 64 + b) * 2048 + 1024 + node]);
                c3[r] = c4[r] = c5[r] = 0.f;
            } else {
                c0[r] = b2f(Go[(b << 10) + node]);
                c1[r] = xin[((b * 12 + t) << 10) + node];
                c2[r] = b2f(S[(size_t)node * ldS + 4096 + b]);
                c3[r] = b2f(XSgT[(size_t)(xsrow + t * 64 + b) * 2048 + node]);
                c4[r] = b2f(S[(size_t)(1024 + node) * ldS + 4096 + b]);
                c5[r] = b2f(XSgT[(size_t)(xsrow + t * 64 + b) * 2048 + 1024 + node]);
            }
        }
#pragma unroll
        for (int j = 0; j < 4; ++j) {
            const int jc = (j << 4) + lr;
            const float bj = bias[jc];
            const float w0 = wx[jc], w1 = wx[64 + jc], w2 = wx[128 + jc];
            float w3 = 0.f, w4 = 0.f, w5 = 0.f;
            if (dec) { w3 = wx[192 + jc]; w4 = wx[256 + jc]; w5 = wx[320 + jc]; }
            u16x4 pack;
            for (int r = 0; r < 4; ++r) {
                float v = acc[i][j][r] + bj + c0[r] * w0 + c1[r] * w1 + c2[r] * w2
                          + c3[r] * w3 + c4[r] * w4 + c5[r] * w5;
                float hc = tanhf(v);
                const int node = node_base + r;
                const size_t idx = ((size_t)(b << 10) + node) * 64 + jc;
                float rr = Rg[idx];
                float hn = rr * H32[idx] + (1.f - rr) * hc;
                H32[idx] = hn;
                unsigned short hb = f2b(hn);
                Hb[idx] = hb;
                pack[r] = hb;
            }
            *(u16x4*)&XhT[(size_t)((b << 6) + jc) * 1024 + node_base] = pack;
        }
    }
}

// ---------------------------------------------------------------------------
// A = softmax(relu(E E^T)) row-wise; one block per row; writes bf16 row.
// ---------------------------------------------------------------------------
__global__ __launch_bounds__(256) void adj_softmax(
    const float* __restrict__ E, unsigned short* __restrict__ A)
{
    __shared__ float Es[8192];
    __shared__ float vals[1024];
    __shared__ float red[8];
    const int tid = threadIdx.x;
    const int r = blockIdx.x;
    for (int i = tid; i < 8192; i += 256) Es[i] = E[i];
    __syncthreads();
    float er[8];
#pragma unroll
    for (int e = 0; e < 8; ++e) er[e] = Es[(r << 3) + e];
    float lmax = -1e30f;
    for (int c = tid; c < 1024; c += 256) {
        float s = 0.f;
#pragma unroll
        for (int e = 0; e < 8; ++e) s += er[e] * Es[(c << 3) + e];
        s = fmaxf(s, 0.f);
        vals[c] = s;
        lmax = fmaxf(lmax, s);
    }
    for (int off = 32; off; off >>= 1) lmax = fmaxf(lmax, __shfl_down(lmax, off, 64));
    if ((tid & 63) == 0) red[tid >> 6] = lmax;
    __syncthreads();
    const float m = fmaxf(fmaxf(red[0], red[1]), fmaxf(red[2], red[3]));
    float lsum = 0.f;
    for (int c = tid; c < 1024; c += 256) {
        float e = __expf(vals[c] - m);
        vals[c] = e;
        lsum += e;
    }
    for (int off = 32; off; off >>= 1) lsum += __shfl_down(lsum, off, 64);
    if ((tid & 63) == 0) red[4 + (tid >> 6)] = lsum;
    __syncthreads();
    const float inv = 1.f / (red[4] + red[5] + red[6] + red[7]);
    for (int c = tid; c < 1024; c += 256)
        A[(r << 10) + c] = f2b(vals[c] * inv);
}

__global__ __launch_bounds__(256) void transpose_bf16(
    const unsigned short* __restrict__ src, unsigned short* __restrict__ dst)
{
    __shared__ unsigned short tile[64][65];
    const int bx = blockIdx.x & 15, by = blockIdx.x >> 4;
    const int x0 = bx << 6, y0 = by << 6;
    for (int i = threadIdx.x; i < 4096; i += 256) {
        const int r = i >> 6, c = i & 63;
        tile[r][c] = src[((y0 + r) << 10) + x0 + c];
    }
    __syncthreads();
    for (int i = threadIdx.x; i < 4096; i += 256) {
        const int r = i >> 6, c = i & 63;
        dst[((x0 + r) << 10) + y0 + c] = tile[c][r];
    }
}

// XallT[(t*64+b), m] = x[b,t,m] (rows 0..767) / y_cov[b,t,m] (rows 768..1535)
__global__ __launch_bounds__(256) void build_xall(
    const float* __restrict__ x, const float* __restrict__ y,
    unsigned short* __restrict__ XallT)
{
    const int id = blockIdx.x * 256 + threadIdx.x;
    const int row = id >> 10, n = id & 1023;
    int t, b;
    const float* src;
    if (row < 768) { t = row >> 6; b = row & 63; src = x; }
    else { const int rr = row - 768; t = rr >> 6; b = rr & 63; src = y; }
    XallT[id] = f2b(src[((b * 12 + t) << 10) + n]);
}

// Weight reorder: MFMA K-layout, h-block weights with W0' = W0 - W2; x/go/y
// rows extracted as fp32 correction tables.
__global__ __launch_bounds__(256) void wprep(
    const float* egW, const float* egb,
    const float* euW, const float* eub,
    const float* dgW, const float* dgb,
    const float* duW, const float* dub,
    const float* pW, const float* pb,
    unsigned short* WgTe, unsigned short* WuTe, unsigned short* WgTd, unsigned short* WuTd,
    float* wxge, float* wxue, float* wxgd, float* wxud,
    float* bge, float* bue, float* bgd, float* bud,
    float* projW, float* projb)
{
    const int tid = threadIdx.x;
    for (int i = tid; i < 128 * 192; i += 256) {
        const int j = i / 192, kk = i % 192, k = kk >> 6, c = kk & 63;
        float v = egW[(k * 65 + 1 + c) * 128 + j];
        if (k == 0) v -= egW[(131 + c) * 128 + j];
        WgTe[i] = f2b(v);
    }
    for (int i = tid; i < 64 * 192; i += 256) {
        const int j = i / 192, kk = i % 192, k = kk >> 6, c = kk & 63;
        float v = euW[(k * 65 + 1 + c) * 64 + j];
        if (k == 0) v -= euW[(131 + c) * 64 + j];
        WuTe[i] = f2b(v);
    }
    for (int i = tid; i < 128 * 192; i += 256) {
        const int j = i / 192, kk = i % 192, k = kk >> 6, c = kk & 63;
        float v = dgW[(k * 66 + 2 + c) * 128 + j];
        if (k == 0) v -= dgW[(134 + c) * 128 + j];
        WgTd[i] = f2b(v);
    }
    for (int i = tid; i < 64 * 192; i += 256) {
        const int j = i / 192, kk = i % 192, k = kk >> 6, c = kk & 63;
        float v = duW[(k * 66 + 2 + c) * 64 + j];
        if (k == 0) v -= duW[(134 + c) * 64 + j];
        WuTd[i] = f2b(v);
    }
    for (int i = tid; i < 384; i += 256) {
        const int k = i >> 7, j = i & 127;
        float v;
        if (k == 0) v = egW[j] - egW[130 * 128 + j];
        else if (k == 1) v = egW[65 * 128 + j];
        else v = egW[130 * 128 + j];
        wxge[i] = v;
    }
    for (int i = tid; i < 192; i += 256) {
        const int k = i >> 6, j = i & 63;
        float v;
        if (k == 0) v = euW[j] - euW[130 * 64 + j];
        else if (k == 1) v = euW[65 * 64 + j];
        else v = euW[130 * 64 + j];
        wxue[i] = v;
    }
    for (int i = tid; i < 768; i += 256) {
        const int k = i >> 7, j = i & 127;
        float v;
        switch (k) {
            case 0: v = dgW[j] - dgW[132 * 128 + j]; break;
            case 1: v = dgW[128 + j] - dgW[133 * 128 + j]; break;
            case 2: v = dgW[66 * 128 + j]; break;
            case 3: v = dgW[67 * 128 + j]; break;
            case 4: v = dgW[132 * 128 + j]; break;
            default: v = dgW[133 * 128 + j]; break;
        }
        wxgd[i] = v;
    }
    for (int i = tid; i < 384; i += 256) {
        const int k = i >> 6, j = i & 63;
        float v;
        switch (k) {
            case 0: v = duW[j] - duW[132 * 64 + j]; break;
            case 1: v = duW[64 + j] - duW[133 * 64 + j]; break;
            case 2: v = duW[66 * 64 + j]; break;
            case 3: v = duW[67 * 64 + j]; break;
            case 4: v = duW[132 * 64 + j]; break;
            default: v = duW[133 * 64 + j]; break;
        }
        wxud[i] = v;
    }
    for (int i = tid; i < 128; i += 256) bge[i] = egb[i];
    for (int i = tid; i < 64; i += 256) bue[i] = eub[i];
    for (int i = tid; i < 128; i += 256) bgd[i] = dgb[i];
    for (int i = tid; i < 64; i += 256) bud[i] = dub[i];
    for (int i = tid; i < 64; i += 256) projW[i] = pW[i];
    if (tid == 0) projb[0] = pb[0];
}

// go = h @ projW + projb; writes Go (bf16), XhT go-rows (bf16), output (fp32).
__global__ __launch_bounds__(256) void proj_kernel(
    const float* __restrict__ H32, const float* __restrict__ projW, const float* __restrict__ projb,
    unsigned short* __restrict__ Go, unsigned short* __restrict__ XhT,
    float* __restrict__ out, int t)
{
    const int w = threadIdx.x >> 6, l = threadIdx.x & 63;
    const int row = (blockIdx.x << 2) + w;  // row = b*1024 + n
    float v = H32[((size_t)row << 6) + l] * projW[l];
#pragma unroll
    for (int off = 32; off; off >>= 1) v += __shfl_down(v, off, 64);
    if (l == 0) {
        const float go = v + projb[0];
        const unsigned short gb = f2b(go);
        const int b = row >> 10, n = row & 1023;
        Go[row] = gb;
        XhT[((size_t)(4096 + b) << 10) + n] = gb;
        out[((size_t)(b * 12 + t) << 10) + n] = go;
    }
}

// ---------------------------------------------------------------------------
extern "C" void kernel_launch(void* const* d_in, const int* in_sizes, int n_in,
                              void* d_out, int out_size, void* d_ws, size_t ws_size,
                              hipStream_t stream)
{
    (void)in_sizes; (void)n_in; (void)out_size; (void)ws_size;
    const float* x    = (const float*)d_in[0];
    const float* ycov = (const float*)d_in[1];
    const float* E    = (const float*)d_in[2];
    const float* egW  = (const float*)d_in[3];
    const float* egb  = (const float*)d_in[4];
    const float* euW  = (const float*)d_in[5];
    const float* eub  = (const float*)d_in[6];
    const float* dgW  = (const float*)d_in[7];
    const float* dgb  = (const float*)d_in[8];
    const float* duW  = (const float*)d_in[9];
    const float* dub  = (const float*)d_in[10];
    const float* pW   = (const float*)d_in[11];
    const float* pb   = (const float*)d_in[12];
    float* out = (float*)d_out;

    size_t off = 0;
    auto carve = [&](size_t bytes) -> void* {
        void* p = (char*)d_ws + off;
        off += (bytes + 255) & ~(size_t)255;
        return p;
    };
    unsigned short* AA    = (unsigned short*)carve(2048ull * 1024 * 2); // [A; 2A^2]
    unsigned short* XSgT  = (unsigned short*)carve(1536ull * 2048 * 2);
    unsigned short* XhT   = (unsigned short*)carve(4224ull * 1024 * 2); // h^T + go rows + pad
    unsigned short* ZhT   = (unsigned short*)carve(4096ull * 1024 * 2);
    unsigned short* S     = (unsigned short*)carve(2048ull * 4224 * 2); // also hosts S2 (cols 0..4095)
    unsigned short* Hb    = (unsigned short*)carve(65536ull * 64 * 2);
    float*          H32   = (float*)carve(65536ull * 64 * 4);
    unsigned short* Zb    = (unsigned short*)carve(65536ull * 64 * 2);
    float*          R     = (float*)carve(65536ull * 64 * 4);
    unsigned short* Go    = (unsigned short*)carve(65536ull * 2);
    unsigned short* WgTe  = (unsigned short*)carve(128ull * 192 * 2);
    unsigned short* WuTe  = (unsigned short*)carve(64ull * 192 * 2);
    unsigned short* WgTd  = (unsigned short*)carve(128ull * 192 * 2);
    unsigned short* WuTd  = (unsigned short*)carve(64ull * 192 * 2);
    float* wxge = (float*)carve(384 * 4);
    float* wxue = (float*)carve(192 * 4);
    float* wxgd = (float*)carve(768 * 4);
    float* wxud = (float*)carve(384 * 4);
    float* bge  = (float*)carve(128 * 4);
    float* bue  = (float*)carve(64 * 4);
    float* bgd  = (float*)carve(128 * 4);
    float* bud  = (float*)carve(64 * 4);
    float* prW  = (float*)carve(64 * 4);
    float* prb  = (float*)carve(4);
    // Aliases: AT and XallT live inside Zb (last use of both precedes Zb's first write).
    unsigned short* AT    = Zb;                      // 1024*1024 elements
    unsigned short* XallT = Zb + 1024ull * 1024;     // 1536*1024 elements (total 2.5M <= 4M)

    hipMemsetAsync(XhT, 0, 4224ull * 1024 * 2, stream);
    hipMemsetAsync(Hb, 0, 65536ull * 64 * 2, stream);
    hipMemsetAsync(H32, 0, 65536ull * 64 * 4, stream);
    hipMemsetAsync(Go, 0, 65536ull * 2, stream);

    adj_softmax<<<1024, 256, 0, stream>>>(E, AA);
    transpose_bf16<<<256, 256, 0, stream>>>(AA, AT);
    // AA[1024:2048] = 2 * A @ A
    gemm_bt<<<dim3(8, 8), 256, 0, stream>>>(AA, 1024, AT, 1024, AA + 1024 * 1024, 1024, 1024, 2.0f);
    build_xall<<<6144, 256, 0, stream>>>(x, ycov, XallT);
    // XSgT[(t,b), r] = ([A;2A^2] @ x_all)[r] for every timestep/batch column
    gemm_bt<<<dim3(16, 12), 256, 0, stream>>>(XallT, 1024, AA, 1024, XSgT, 2048, 1024, 1.0f);
    wprep<<<1, 256, 0, stream>>>(egW, egb, euW, eub, dgW, dgb, duW, dub, pW, pb,
                                 WgTe, WuTe, WgTd, WuTd, wxge, wxue, wxgd, wxud,
                                 bge, bue, bgd, bud, prW, prb);

    for (int t = 0; t < 12; ++t) {  // encoder
        gemm_bt<<<dim3(32, 16), 256, 0, stream>>>(AA, 1024, XhT, 1024, S, 4224, 1024, 1.0f);
        gru_gate<<<512, 256, 0, stream>>>(Hb, S, 4224, WgTe, bge, wxge, x, t, XSgT, 0, Go, H32,
                                          Zb, ZhT, R, 0);
        gemm_bt<<<dim3(32, 16), 256, 0, stream>>>(AA, 1024, ZhT, 1024, S, 4224, 1024, 1.0f);
        gru_update<<<512, 256, 0, stream>>>(Zb, S, 4224, WuTe, bue, wxue, x, t, XSgT, 0, Go,
                                            R, H32, Hb, XhT, 0);
    }
    for (int t = 0; t < 12; ++t) {  // decoder
        gemm_bt<<<dim3(33, 16), 256, 0, stream>>>(AA, 1024, XhT, 1024, S, 4224, 1024, 1.0f);
        gru_gate<<<512, 256, 0, stream>>>(Hb, S, 4224, WgTd, bgd, wxgd, ycov, t, XSgT, 768, Go, H32,
                                          Zb, ZhT, R, 1);
        gemm_bt<<<dim3(32, 16), 256, 0, stream>>>(AA, 1024, ZhT, 1024, S, 4224, 1024, 1.0f);
        gru_update<<<512, 256, 0, stream>>>(Zb, S, 4224, WuTd, bud, wxud, ycov, t, XSgT, 768, Go,
                                            R, H32, Hb, XhT, 1);
        proj_kernel<<<16384, 256, 0, stream>>>(H32, prW, prb, Go, XhT, out, t);
    }
}

// Round 4
// 2737.043 us; speedup vs baseline: 1.1134x; 1.1134x over previous
//
#include <hip/hip_runtime.h>

// GCRN (AGCRN-style) on gfx950. Inputs/outputs fp32; internal compute bf16 MFMA.
// A = softmax(relu(E E^T)); AA = [A; 2A^2] stacked (T2 = 2A^2 - I folded into
// weights: W0' = W0 - W2). Per GRU cell: S = AA @ h (bf16 MFMA), then fused
// gate/update GEMMs (K=192 over [h, A h, 2A^2 h]) with rank-1 x/go/y corrections
// in the epilogue. h state fp32; MFMA operands bf16, K-contiguous.
// Round 4: global_load_lds width-16 staging (m97 pattern), wprep over 64 blocks,
// proj fused into decoder gru_update epilogue (shuffle reduction).

typedef __attribute__((ext_vector_type(8))) short bf16x8;
typedef __attribute__((ext_vector_type(4))) float f32x4;
typedef __attribute__((ext_vector_type(4))) unsigned short u16x4;

__device__ __forceinline__ float b2f(unsigned short u) {
    union { unsigned int i; float f; } v; v.i = ((unsigned int)u) << 16; return v.f;
}
__device__ __forceinline__ unsigned short f2b(float f) {
    union { float f; unsigned int i; } v; v.f = f;
    unsigned int r = v.i + 0x7FFFu + ((v.i >> 16) & 1u);
    return (unsigned short)(r >> 16);
}

// LDS dest must be wave-uniform base + lane*16 (m104/m108). Our staging offset
// is exactly tid*16 bytes within each tile half -> legal.
#define GLOAD_LDS16(g, l) __builtin_amdgcn_global_load_lds( \
    (const __attribute__((address_space(1))) void*)(g),     \
    (__attribute__((address_space(3))) void*)(l), 16, 0, 0)

// ---------------------------------------------------------------------------
// Generic bf16 GEMM: C[m,n] = scale * sum_k P[m,k] * QT[n,k].  (both K-contig)
// grid.x = N/128, grid.y = M/128, 256 threads. m97-style single-buffered.
// ---------------------------------------------------------------------------
__global__ __launch_bounds__(256) void gemm_bt(
    const unsigned short* __restrict__ P, int lda,
    const unsigned short* __restrict__ QT, int ldb,
    unsigned short* __restrict__ C, int ldc,
    int K, float scale)
{
    __shared__ __align__(16) unsigned short As[128 * 32];
    __shared__ __align__(16) unsigned short Bs[128 * 32];
    const int tid = threadIdx.x;
    const int m0 = blockIdx.y << 7, n0 = blockIdx.x << 7;
    const int w = tid >> 6, l = tid & 63;
    const int wm = (w >> 1) << 6, wn = (w & 1) << 6;
    const int lr = l & 15, lq = l >> 4;
    const int arow = tid >> 2, ak = (tid & 3) << 3;
    f32x4 acc[4][4] = {};

    for (int k0 = 0; k0 < K; k0 += 32) {
#pragma unroll
        for (int p = 0; p < 2; ++p)
            GLOAD_LDS16(P + (size_t)(m0 + arow + (p << 6)) * lda + k0 + ak,
                        &As[((arow + (p << 6)) << 5) + ak]);
#pragma unroll
        for (int p = 0; p < 2; ++p)
            GLOAD_LDS16(QT + (size_t)(n0 + arow + (p << 6)) * ldb + k0 + ak,
                        &Bs[((arow + (p << 6)) << 5) + ak]);
        __syncthreads();
        bf16x8 a[4], b[4];
#pragma unroll
        for (int i = 0; i < 4; ++i)
            a[i] = *(const bf16x8*)&As[((wm + (i << 4) + lr) << 5) + (lq << 3)];
#pragma unroll
        for (int j = 0; j < 4; ++j)
            b[j] = *(const bf16x8*)&Bs[((wn + (j << 4) + lr) << 5) + (lq << 3)];
#pragma unroll
        for (int i = 0; i < 4; ++i)
#pragma unroll
            for (int j = 0; j < 4; ++j)
                acc[i][j] = __builtin_amdgcn_mfma_f32_16x16x32_bf16(a[i], b[j], acc[i][j], 0, 0, 0);
        __syncthreads();
    }
#pragma unroll
    for (int i = 0; i < 4; ++i)
#pragma unroll
        for (int j = 0; j < 4; ++j)
#pragma unroll
            for (int r = 0; r < 4; ++r) {
                const int m = m0 + wm + (i << 4) + (lq << 2) + r;
                const int n = n0 + wn + (j << 4) + lr;
                C[(size_t)m * ldc + n] = f2b(acc[i][j][r] * scale);
            }
}

// ---------------------------------------------------------------------------
// Fused gate GEMM: zr = sigmoid( [h | A h | 2A^2 h] @ W' + bias + corr )
// grid 512 (b in [0,64), node-tile in [0,8)), N=128, K=192.
// z (cols 0..63) -> Zb = z*h (b,n,c) + ZhT (b,c,n);  r (cols 64..127) -> R fp32.
// ---------------------------------------------------------------------------
__global__ __launch_bounds__(256) void gru_gate(
    const unsigned short* __restrict__ Hb, const unsigned short* __restrict__ S, int ldS,
    const unsigned short* __restrict__ WT, const float* __restrict__ bias,
    const float* __restrict__ wx, const float* __restrict__ xin, int t,
    const unsigned short* __restrict__ XSgT, int xsrow, const unsigned short* __restrict__ Go,
    const float* __restrict__ H32,
    unsigned short* __restrict__ Zb, unsigned short* __restrict__ ZhT, float* __restrict__ R,
    int dec)
{
    __shared__ __align__(16) unsigned short As[128 * 32];
    __shared__ __align__(16) unsigned short Bs[128 * 32];
    const int tid = threadIdx.x;
    const int rb = blockIdx.x;
    const int b = rb >> 3, n0 = (rb & 7) << 7;
    const int w = tid >> 6, l = tid & 63;
    const int wm = (w >> 1) << 6, wn = (w & 1) << 6;
    const int lr = l & 15, lq = l >> 4;
    const int arow = tid >> 2, ak = (tid & 3) << 3;
    f32x4 acc[4][4] = {};

    const unsigned short* sbase[3];
    size_t sstride[3];
    sbase[0] = Hb + ((size_t)(b << 10) + n0) * 64;        sstride[0] = 64;
    sbase[1] = S + (size_t)n0 * ldS + (b << 6);           sstride[1] = (size_t)ldS;
    sbase[2] = S + (size_t)(1024 + n0) * ldS + (b << 6);  sstride[2] = (size_t)ldS;

    for (int kk0 = 0; kk0 < 192; kk0 += 32) {
        const int seg = kk0 >> 6, so = kk0 & 63;
#pragma unroll
        for (int p = 0; p < 2; ++p)
            GLOAD_LDS16(sbase[seg] + (size_t)(arow + (p << 6)) * sstride[seg] + so + ak,
                        &As[((arow + (p << 6)) << 5) + ak]);
#pragma unroll
        for (int p = 0; p < 2; ++p)
            GLOAD_LDS16(WT + (size_t)(arow + (p << 6)) * 192 + kk0 + ak,
                        &Bs[((arow + (p << 6)) << 5) + ak]);
        __syncthreads();
        bf16x8 a[4], bb[4];
#pragma unroll
        for (int i = 0; i < 4; ++i)
            a[i] = *(const bf16x8*)&As[((wm + (i << 4) + lr) << 5) + (lq << 3)];
#pragma unroll
        for (int j = 0; j < 4; ++j)
            bb[j] = *(const bf16x8*)&Bs[((wn + (j << 4) + lr) << 5) + (lq << 3)];
#pragma unroll
        for (int i = 0; i < 4; ++i)
#pragma unroll
            for (int j = 0; j < 4; ++j)
                acc[i][j] = __builtin_amdgcn_mfma_f32_16x16x32_bf16(a[i], bb[j], acc[i][j], 0, 0, 0);
        __syncthreads();
    }

#pragma unroll
    for (int i = 0; i < 4; ++i) {
        const int node_base = n0 + wm + (i << 4) + (lq << 2);
        float c0[4], c1[4], c2[4], c3[4], c4[4], c5[4];
        for (int r = 0; r < 4; ++r) {
            const int node = node_base + r;
            if (!dec) {
                c0[r] = xin[((b * 12 + t) << 10) + node];
                c1[r] = b2f(XSgT[(size_t)(xsrow + t * 64 + b) * 2048 + node]);
                c2[r] = b2f(XSgT[(size_t)(xsrow + t * 64 + b) * 2048 + 1024 + node]);
                c3[r] = c4[r] = c5[r] = 0.f;
            } else {
                c0[r] = b2f(Go[(b << 10) + node]);
                c1[r] = xin[((b * 12 + t) << 10) + node];
                c2[r] = b2f(S[(size_t)node * ldS + 4096 + b]);
                c3[r] = b2f(XSgT[(size_t)(xsrow + t * 64 + b) * 2048 + node]);
                c4[r] = b2f(S[(size_t)(1024 + node) * ldS + 4096 + b]);
                c5[r] = b2f(XSgT[(size_t)(xsrow + t * 64 + b) * 2048 + 1024 + node]);
            }
        }
#pragma unroll
        for (int j = 0; j < 4; ++j) {
            const int jc = wn + (j << 4) + lr;
            const float bj = bias[jc];
            const float w0 = wx[jc], w1 = wx[128 + jc], w2 = wx[256 + jc];
            float w3 = 0.f, w4 = 0.f, w5 = 0.f;
            if (dec) { w3 = wx[384 + jc]; w4 = wx[512 + jc]; w5 = wx[640 + jc]; }
            if (jc < 64) {
                u16x4 pack;
                for (int r = 0; r < 4; ++r) {
                    float v = acc[i][j][r] + bj + c0[r] * w0 + c1[r] * w1 + c2[r] * w2
                              + c3[r] * w3 + c4[r] * w4 + c5[r] * w5;
                    float g = 1.f / (1.f + __expf(-v));
                    const int node = node_base + r;
                    const size_t idx = ((size_t)(b << 10) + node) * 64 + jc;
                    float zh = g * H32[idx];
                    unsigned short zb = f2b(zh);
                    Zb[idx] = zb;
                    pack[r] = zb;
                }
                *(u16x4*)&ZhT[(size_t)((b << 6) + jc) * 1024 + node_base] = pack;
            } else {
                for (int r = 0; r < 4; ++r) {
                    float v = acc[i][j][r] + bj + c0[r] * w0 + c1[r] * w1 + c2[r] * w2
                              + c3[r] * w3 + c4[r] * w4 + c5[r] * w5;
                    float g = 1.f / (1.f + __expf(-v));
                    const int node = node_base + r;
                    R[((size_t)(b << 10) + node) * 64 + (jc - 64)] = g;
                }
            }
        }
    }
}

// ---------------------------------------------------------------------------
// Fused update GEMM: hc = tanh([zh | A zh | 2A^2 zh] @ Wu' + bias + corr);
// h' = r*h + (1-r)*hc.  N=64.  Writes H32 (fp32), Hb (b,n,c), XhT (b,c,n).
// Decoder (dec=1): also computes go = h' @ projW + projb in-register via
// intra-16-lane shuffle reduction; writes Go, XhT go-rows, out[:, t].
// ---------------------------------------------------------------------------
__global__ __launch_bounds__(256) void gru_update(
    const unsigned short* __restrict__ Zb, const unsigned short* __restrict__ S, int ldS,
    const unsigned short* __restrict__ WT, const float* __restrict__ bias,
    const float* __restrict__ wx, const float* __restrict__ xin, int t,
    const unsigned short* __restrict__ XSgT, int xsrow, const unsigned short* __restrict__ Go,
    const float* __restrict__ Rg,
    float* __restrict__ H32, unsigned short* __restrict__ Hb, unsigned short* __restrict__ XhT,
    const float* __restrict__ prW, const float* __restrict__ prb,
    unsigned short* __restrict__ GoOut, float* __restrict__ outp,
    int dec)
{
    __shared__ __align__(16) unsigned short As[128 * 32];
    __shared__ __align__(16) unsigned short Bs[64 * 32];
    const int tid = threadIdx.x;
    const int rb = blockIdx.x;
    const int b = rb >> 3, n0 = (rb & 7) << 7;
    const int w = tid >> 6, l = tid & 63;
    const int wm = w << 5;
    const int lr = l & 15, lq = l >> 4;
    const int arow = tid >> 2, ak = (tid & 3) << 3;
    f32x4 acc[2][4] = {};

    const unsigned short* sbase[3];
    size_t sstride[3];
    sbase[0] = Zb + ((size_t)(b << 10) + n0) * 64;        sstride[0] = 64;
    sbase[1] = S + (size_t)n0 * ldS + (b << 6);           sstride[1] = (size_t)ldS;
    sbase[2] = S + (size_t)(1024 + n0) * ldS + (b << 6);  sstride[2] = (size_t)ldS;

    for (int kk0 = 0; kk0 < 192; kk0 += 32) {
        const int seg = kk0 >> 6, so = kk0 & 63;
#pragma unroll
        for (int p = 0; p < 2; ++p)
            GLOAD_LDS16(sbase[seg] + (size_t)(arow + (p << 6)) * sstride[seg] + so + ak,
                        &As[((arow + (p << 6)) << 5) + ak]);
        GLOAD_LDS16(WT + (size_t)arow * 192 + kk0 + ak, &Bs[(arow << 5) + ak]);
        __syncthreads();
        bf16x8 a[2], bb[4];
#pragma unroll
        for (int i = 0; i < 2; ++i)
            a[i] = *(const bf16x8*)&As[((wm + (i << 4) + lr) << 5) + (lq << 3)];
#pragma unroll
        for (int j = 0; j < 4; ++j)
            bb[j] = *(const bf16x8*)&Bs[(((j << 4) + lr) << 5) + (lq << 3)];
#pragma unroll
        for (int i = 0; i < 2; ++i)
#pragma unroll
            for (int j = 0; j < 4; ++j)
                acc[i][j] = __builtin_amdgcn_mfma_f32_16x16x32_bf16(a[i], bb[j], acc[i][j], 0, 0, 0);
        __syncthreads();
    }

    float pw[4];
    if (dec) {
#pragma unroll
        for (int j = 0; j < 4; ++j) pw[j] = prW[(j << 4) + lr];
    }

#pragma unroll
    for (int i = 0; i < 2; ++i) {
        const int node_base = n0 + wm + (i << 4) + (lq << 2);
        float c0[4], c1[4], c2[4], c3[4], c4[4], c5[4];
        for (int r = 0; r < 4; ++r) {
            const int node = node_base + r;
            if (!dec) {
                c0[r] = xin[((b * 12 + t) << 10) + node];
                c1[r] = b2f(XSgT[(size_t)(xsrow + t * 64 + b) * 2048 + node]);
                c2[r] = b2f(XSgT[(size_t)(xsrow + t * 64 + b) * 2048 + 1024 + node]);
                c3[r] = c4[r] = c5[r] = 0.f;
            } else {
                c0[r] = b2f(Go[(b << 10) + node]);
                c1[r] = xin[((b * 12 + t) << 10) + node];
                c2[r] = b2f(S[(size_t)node * ldS + 4096 + b]);
                c3[r] = b2f(XSgT[(size_t)(xsrow + t * 64 + b) * 2048 + node]);
                c4[r] = b2f(S[(size_t)(1024 + node) * ldS + 4096 + b]);
                c5[r] = b2f(XSgT[(size_t)(xsrow + t * 64 + b) * 2048 + 1024 + node]);
            }
        }
        float psum[4] = {0.f, 0.f, 0.f, 0.f};
#pragma unroll
        for (int j = 0; j < 4; ++j) {
            const int jc = (j << 4) + lr;
            const float bj = bias[jc];
            const float w0 = wx[jc], w1 = wx[64 + jc], w2 = wx[128 + jc];
            float w3 = 0.f, w4 = 0.f, w5 = 0.f;
            if (dec) { w3 = wx[192 + jc]; w4 = wx[256 + jc]; w5 = wx[320 + jc]; }
            u16x4 pack;
            for (int r = 0; r < 4; ++r) {
                float v = acc[i][j][r] + bj + c0[r] * w0 + c1[r] * w1 + c2[r] * w2
                          + c3[r] * w3 + c4[r] * w4 + c5[r] * w5;
                float hc = tanhf(v);
                const int node = node_base + r;
                const size_t idx = ((size_t)(b << 10) + node) * 64 + jc;
                float rr = Rg[idx];
                float hn = rr * H32[idx] + (1.f - rr) * hc;
                H32[idx] = hn;
                unsigned short hb = f2b(hn);
                Hb[idx] = hb;
                pack[r] = hb;
                if (dec) psum[r] += hn * pw[j];
            }
            *(u16x4*)&XhT[(size_t)((b << 6) + jc) * 1024 + node_base] = pack;
        }
        if (dec) {
#pragma unroll
            for (int r = 0; r < 4; ++r) {
                float v = psum[r];
                v += __shfl_down(v, 8, 16);
                v += __shfl_down(v, 4, 16);
                v += __shfl_down(v, 2, 16);
                v += __shfl_down(v, 1, 16);
                if (lr == 0) {
                    const int node = node_base + r;
                    const float go = v + prb[0];
                    GoOut[(b << 10) + node] = f2b(go);
                    XhT[((size_t)(4096 + b) << 10) + node] = f2b(go);
                    outp[((size_t)(b * 12 + t) << 10) + node] = go;
                }
            }
        }
    }
}

// ---------------------------------------------------------------------------
// A = softmax(relu(E E^T)) row-wise; one block per row; writes bf16 row.
// ---------------------------------------------------------------------------
__global__ __launch_bounds__(256) void adj_softmax(
    const float* __restrict__ E, unsigned short* __restrict__ A)
{
    __shared__ float Es[8192];
    __shared__ float vals[1024];
    __shared__ float red[8];
    const int tid = threadIdx.x;
    const int r = blockIdx.x;
    for (int i = tid; i < 8192; i += 256) Es[i] = E[i];
    __syncthreads();
    float er[8];
#pragma unroll
    for (int e = 0; e < 8; ++e) er[e] = Es[(r << 3) + e];
    float lmax = -1e30f;
    for (int c = tid; c < 1024; c += 256) {
        float s = 0.f;
#pragma unroll
        for (int e = 0; e < 8; ++e) s += er[e] * Es[(c << 3) + e];
        s = fmaxf(s, 0.f);
        vals[c] = s;
        lmax = fmaxf(lmax, s);
    }
    for (int off = 32; off; off >>= 1) lmax = fmaxf(lmax, __shfl_down(lmax, off, 64));
    if ((tid & 63) == 0) red[tid >> 6] = lmax;
    __syncthreads();
    const float m = fmaxf(fmaxf(red[0], red[1]), fmaxf(red[2], red[3]));
    float lsum = 0.f;
    for (int c = tid; c < 1024; c += 256) {
        float e = __expf(vals[c] - m);
        vals[c] = e;
        lsum += e;
    }
    for (int off = 32; off; off >>= 1) lsum += __shfl_down(lsum, off, 64);
    if ((tid & 63) == 0) red[4 + (tid >> 6)] = lsum;
    __syncthreads();
    const float inv = 1.f / (red[4] + red[5] + red[6] + red[7]);
    for (int c = tid; c < 1024; c += 256)
        A[(r << 10) + c] = f2b(vals[c] * inv);
}

__global__ __launch_bounds__(256) void transpose_bf16(
    const unsigned short* __restrict__ src, unsigned short* __restrict__ dst)
{
    __shared__ unsigned short tile[64][65];
    const int bx = blockIdx.x & 15, by = blockIdx.x >> 4;
    const int x0 = bx << 6, y0 = by << 6;
    for (int i = threadIdx.x; i < 4096; i += 256) {
        const int r = i >> 6, c = i & 63;
        tile[r][c] = src[((y0 + r) << 10) + x0 + c];
    }
    __syncthreads();
    for (int i = threadIdx.x; i < 4096; i += 256) {
        const int r = i >> 6, c = i & 63;
        dst[((x0 + r) << 10) + y0 + c] = tile[c][r];
    }
}

// XallT[(t*64+b), m] = x[b,t,m] (rows 0..767) / y_cov[b,t,m] (rows 768..1535)
__global__ __launch_bounds__(256) void build_xall(
    const float* __restrict__ x, const float* __restrict__ y,
    unsigned short* __restrict__ XallT)
{
    const int id = blockIdx.x * 256 + threadIdx.x;
    const int row = id >> 10, n = id & 1023;
    int t, b;
    const float* src;
    if (row < 768) { t = row >> 6; b = row & 63; src = x; }
    else { const int rr = row - 768; t = rr >> 6; b = rr & 63; src = y; }
    XallT[id] = f2b(src[((b * 12 + t) << 10) + n]);
}

// Weight reorder: MFMA K-layout, h-block weights with W0' = W0 - W2; x/go/y
// rows extracted as fp32 correction tables. Grid-strided over 64 blocks.
__global__ __launch_bounds__(256) void wprep(
    const float* egW, const float* egb,
    const float* euW, const float* eub,
    const float* dgW, const float* dgb,
    const float* duW, const float* dub,
    const float* pW, const float* pb,
    unsigned short* WgTe, unsigned short* WuTe, unsigned short* WgTd, unsigned short* WuTd,
    float* wxge, float* wxue, float* wxgd, float* wxud,
    float* bge, float* bue, float* bgd, float* bud,
    float* projW, float* projb)
{
    const int tid0 = blockIdx.x * 256 + threadIdx.x;
    const int stride = 256 * gridDim.x;
    for (int i = tid0; i < 128 * 192; i += stride) {
        const int j = i / 192, kk = i % 192, k = kk >> 6, c = kk & 63;
        float v = egW[(k * 65 + 1 + c) * 128 + j];
        if (k == 0) v -= egW[(131 + c) * 128 + j];
        WgTe[i] = f2b(v);
    }
    for (int i = tid0; i < 64 * 192; i += stride) {
        const int j = i / 192, kk = i % 192, k = kk >> 6, c = kk & 63;
        float v = euW[(k * 65 + 1 + c) * 64 + j];
        if (k == 0) v -= euW[(131 + c) * 64 + j];
        WuTe[i] = f2b(v);
    }
    for (int i = tid0; i < 128 * 192; i += stride) {
        const int j = i / 192, kk = i % 192, k = kk >> 6, c = kk & 63;
        float v = dgW[(k * 66 + 2 + c) * 128 + j];
        if (k == 0) v -= dgW[(134 + c) * 128 + j];
        WgTd[i] = f2b(v);
    }
    for (int i = tid0; i < 64 * 192; i += stride) {
        const int j = i / 192, kk = i % 192, k = kk >> 6, c = kk & 63;
        float v = duW[(k * 66 + 2 + c) * 64 + j];
        if (k == 0) v -= duW[(134 + c) * 64 + j];
        WuTd[i] = f2b(v);
    }
    for (int i = tid0; i < 384; i += stride) {
        const int k = i >> 7, j = i & 127;
        float v;
        if (k == 0) v = egW[j] - egW[130 * 128 + j];
        else if (k == 1) v = egW[65 * 128 + j];
        else v = egW[130 * 128 + j];
        wxge[i] = v;
    }
    for (int i = tid0; i < 192; i += stride) {
        const int k = i >> 6, j = i & 63;
        float v;
        if (k == 0) v = euW[j] - euW[130 * 64 + j];
        else if (k == 1) v = euW[65 * 64 + j];
        else v = euW[130 * 64 + j];
        wxue[i] = v;
    }
    for (int i = tid0; i < 768; i += stride) {
        const int k = i >> 7, j = i & 127;
        float v;
        switch (k) {
            case 0: v = dgW[j] - dgW[132 * 128 + j]; break;
            case 1: v = dgW[128 + j] - dgW[133 * 128 + j]; break;
            case 2: v = dgW[66 * 128 + j]; break;
            case 3: v = dgW[67 * 128 + j]; break;
            case 4: v = dgW[132 * 128 + j]; break;
            default: v = dgW[133 * 128 + j]; break;
        }
        wxgd[i] = v;
    }
    for (int i = tid0; i < 384; i += stride) {
        const int k = i >> 6, j = i & 63;
        float v;
        switch (k) {
            case 0: v = duW[j] - duW[132 * 64 + j]; break;
            case 1: v = duW[64 + j] - duW[133 * 64 + j]; break;
            case 2: v = duW[66 * 64 + j]; break;
            case 3: v = duW[67 * 64 + j]; break;
            case 4: v = duW[132 * 64 + j]; break;
            default: v = duW[133 * 64 + j]; break;
        }
        wxud[i] = v;
    }
    for (int i = tid0; i < 128; i += stride) bge[i] = egb[i];
    for (int i = tid0; i < 64; i += stride) bue[i] = eub[i];
    for (int i = tid0; i < 128; i += stride) bgd[i] = dgb[i];
    for (int i = tid0; i < 64; i += stride) bud[i] = dub[i];
    for (int i = tid0; i < 64; i += stride) projW[i] = pW[i];
    if (tid0 == 0) projb[0] = pb[0];
}

// ---------------------------------------------------------------------------
extern "C" void kernel_launch(void* const* d_in, const int* in_sizes, int n_in,
                              void* d_out, int out_size, void* d_ws, size_t ws_size,
                              hipStream_t stream)
{
    (void)in_sizes; (void)n_in; (void)out_size; (void)ws_size;
    const float* x    = (const float*)d_in[0];
    const float* ycov = (const float*)d_in[1];
    const float* E    = (const float*)d_in[2];
    const float* egW  = (const float*)d_in[3];
    const float* egb  = (const float*)d_in[4];
    const float* euW  = (const float*)d_in[5];
    const float* eub  = (const float*)d_in[6];
    const float* dgW  = (const float*)d_in[7];
    const float* dgb  = (const float*)d_in[8];
    const float* duW  = (const float*)d_in[9];
    const float* dub  = (const float*)d_in[10];
    const float* pW   = (const float*)d_in[11];
    const float* pb   = (const float*)d_in[12];
    float* out = (float*)d_out;

    size_t off = 0;
    auto carve = [&](size_t bytes) -> void* {
        void* p = (char*)d_ws + off;
        off += (bytes + 255) & ~(size_t)255;
        return p;
    };
    unsigned short* AA    = (unsigned short*)carve(2048ull * 1024 * 2); // [A; 2A^2]
    unsigned short* XSgT  = (unsigned short*)carve(1536ull * 2048 * 2);
    unsigned short* XhT   = (unsigned short*)carve(4224ull * 1024 * 2); // h^T + go rows + pad
    unsigned short* ZhT   = (unsigned short*)carve(4096ull * 1024 * 2);
    unsigned short* S     = (unsigned short*)carve(2048ull * 4224 * 2); // also hosts S2 (cols 0..4095)
    unsigned short* Hb    = (unsigned short*)carve(65536ull * 64 * 2);
    float*          H32   = (float*)carve(65536ull * 64 * 4);
    unsigned short* Zb    = (unsigned short*)carve(65536ull * 64 * 2);
    float*          R     = (float*)carve(65536ull * 64 * 4);
    unsigned short* Go    = (unsigned short*)carve(65536ull * 2);
    unsigned short* WgTe  = (unsigned short*)carve(128ull * 192 * 2);
    unsigned short* WuTe  = (unsigned short*)carve(64ull * 192 * 2);
    unsigned short* WgTd  = (unsigned short*)carve(128ull * 192 * 2);
    unsigned short* WuTd  = (unsigned short*)carve(64ull * 192 * 2);
    float* wxge = (float*)carve(384 * 4);
    float* wxue = (float*)carve(192 * 4);
    float* wxgd = (float*)carve(768 * 4);
    float* wxud = (float*)carve(384 * 4);
    float* bge  = (float*)carve(128 * 4);
    float* bue  = (float*)carve(64 * 4);
    float* bgd  = (float*)carve(128 * 4);
    float* bud  = (float*)carve(64 * 4);
    float* prW  = (float*)carve(64 * 4);
    float* prb  = (float*)carve(4);
    // Aliases: AT and XallT live inside Zb (last use of both precedes Zb's first write).
    unsigned short* AT    = Zb;                      // 1024*1024 elements
    unsigned short* XallT = Zb + 1024ull * 1024;     // 1536*1024 elements (total 2.5M <= 4M)

    hipMemsetAsync(XhT, 0, 4224ull * 1024 * 2, stream);
    hipMemsetAsync(Hb, 0, 65536ull * 64 * 2, stream);
    hipMemsetAsync(H32, 0, 65536ull * 64 * 4, stream);
    hipMemsetAsync(Go, 0, 65536ull * 2, stream);

    adj_softmax<<<1024, 256, 0, stream>>>(E, AA);
    transpose_bf16<<<256, 256, 0, stream>>>(AA, AT);
    // AA[1024:2048] = 2 * A @ A
    gemm_bt<<<dim3(8, 8), 256, 0, stream>>>(AA, 1024, AT, 1024, AA + 1024 * 1024, 1024, 1024, 2.0f);
    build_xall<<<6144, 256, 0, stream>>>(x, ycov, XallT);
    // XSgT[(t,b), r] = ([A;2A^2] @ x_all)[r] for every timestep/batch column
    gemm_bt<<<dim3(16, 12), 256, 0, stream>>>(XallT, 1024, AA, 1024, XSgT, 2048, 1024, 1.0f);
    wprep<<<64, 256, 0, stream>>>(egW, egb, euW, eub, dgW, dgb, duW, dub, pW, pb,
                                  WgTe, WuTe, WgTd, WuTd, wxge, wxue, wxgd, wxud,
                                  bge, bue, bgd, bud, prW, prb);

    for (int t = 0; t < 12; ++t) {  // encoder
        gemm_bt<<<dim3(32, 16), 256, 0, stream>>>(AA, 1024, XhT, 1024, S, 4224, 1024, 1.0f);
        gru_gate<<<512, 256, 0, stream>>>(Hb, S, 4224, WgTe, bge, wxge, x, t, XSgT, 0, Go, H32,
                                          Zb, ZhT, R, 0);
        gemm_bt<<<dim3(32, 16), 256, 0, stream>>>(AA, 1024, ZhT, 1024, S, 4224, 1024, 1.0f);
        gru_update<<<512, 256, 0, stream>>>(Zb, S, 4224, WuTe, bue, wxue, x, t, XSgT, 0, Go,
                                            R, H32, Hb, XhT, prW, prb, Go, out, 0);
    }
    for (int t = 0; t < 12; ++t) {  // decoder
        gemm_bt<<<dim3(33, 16), 256, 0, stream>>>(AA, 1024, XhT, 1024, S, 4224, 1024, 1.0f);
        gru_gate<<<512, 256, 0, stream>>>(Hb, S, 4224, WgTd, bgd, wxgd, ycov, t, XSgT, 768, Go, H32,
                                          Zb, ZhT, R, 1);
        gemm_bt<<<dim3(32, 16), 256, 0, stream>>>(AA, 1024, ZhT, 1024, S, 4224, 1024, 1.0f);
        gru_update<<<512, 256, 0, stream>>>(Zb, S, 4224, WuTd, bud, wxud, ycov, t, XSgT, 768, Go,
                                            R, H32, Hb, XhT, prW, prb, Go, out, 1);
    }
}

// Round 6
// 2455.260 us; speedup vs baseline: 1.2411x; 1.1148x over previous
//
#include <hip/hip_runtime.h>

// GCRN (AGCRN-style) on gfx950. Inputs/outputs fp32; internal compute bf16 MFMA.
// A = softmax(relu(E E^T)); AA = [A; 2A^2] stacked (T2 = 2A^2 - I folded into
// weights: W0' = W0 - W2).
// Fully fused cells, two dispatches per cell:
//   cell_gate:   phase1 Sh = AA[rows n0,1024+n0] @ XhT[b-rows]^T (K=1024, in-reg
//                -> LDS); decoder go-gather analytic: A@go = Sh@prW + prb·rowsum
//                (rowsum(A)=1, rowsum(2A^2)=2) — EXCEPT t=0 where go=0 (GO token)
//                -> Sgo/SgoS zeroed (goflag).
//   cell_update: phase1 Sz = AA @ ZhT^T; phase2 hc = tanh(...); h'=r h+(1-r)hc
//                -> H32, Hb, XhT; decoder: fused proj -> Go, out.
// No S matrix in global memory; gather output never leaves the CU.

typedef __attribute__((ext_vector_type(8))) short bf16x8;
typedef __attribute__((ext_vector_type(4))) float f32x4;
typedef __attribute__((ext_vector_type(4))) unsigned short u16x4;

__device__ __forceinline__ float b2f(unsigned short u) {
    union { unsigned int i; float f; } v; v.i = ((unsigned int)u) << 16; return v.f;
}
__device__ __forceinline__ unsigned short f2b(float f) {
    union { float f; unsigned int i; } v; v.f = f;
    unsigned int r = v.i + 0x7FFFu + ((v.i >> 16) & 1u);
    return (unsigned short)(r >> 16);
}

// LDS dest is wave-uniform base + lane*16 in every use below (m104/m108 rule).
#define GLOAD_LDS16(g, l) __builtin_amdgcn_global_load_lds( \
    (const __attribute__((address_space(1))) void*)(g),     \
    (__attribute__((address_space(3))) void*)(l), 16, 0, 0)

// ---------------------------------------------------------------------------
// Generic bf16 GEMM (preamble only): C[m,n] = scale * sum_k P[m,k]*QT[n,k].
// ---------------------------------------------------------------------------
__global__ __launch_bounds__(256) void gemm_bt(
    const unsigned short* __restrict__ P, int lda,
    const unsigned short* __restrict__ QT, int ldb,
    unsigned short* __restrict__ C, int ldc,
    int K, float scale)
{
    __shared__ __align__(16) unsigned short As[128 * 32];
    __shared__ __align__(16) unsigned short Bs[128 * 32];
    const int tid = threadIdx.x;
    const int m0 = blockIdx.y << 7, n0 = blockIdx.x << 7;
    const int w = tid >> 6, l = tid & 63;
    const int wm = (w >> 1) << 6, wn = (w & 1) << 6;
    const int lr = l & 15, lq = l >> 4;
    const int arow = tid >> 2, ak = (tid & 3) << 3;
    f32x4 acc[4][4] = {};

    for (int k0 = 0; k0 < K; k0 += 32) {
#pragma unroll
        for (int p = 0; p < 2; ++p)
            GLOAD_LDS16(P + (size_t)(m0 + arow + (p << 6)) * lda + k0 + ak,
                        &As[((arow + (p << 6)) << 5) + ak]);
#pragma unroll
        for (int p = 0; p < 2; ++p)
            GLOAD_LDS16(QT + (size_t)(n0 + arow + (p << 6)) * ldb + k0 + ak,
                        &Bs[((arow + (p << 6)) << 5) + ak]);
        __syncthreads();
        bf16x8 a[4], b[4];
#pragma unroll
        for (int i = 0; i < 4; ++i)
            a[i] = *(const bf16x8*)&As[((wm + (i << 4) + lr) << 5) + (lq << 3)];
#pragma unroll
        for (int j = 0; j < 4; ++j)
            b[j] = *(const bf16x8*)&Bs[((wn + (j << 4) + lr) << 5) + (lq << 3)];
#pragma unroll
        for (int i = 0; i < 4; ++i)
#pragma unroll
            for (int j = 0; j < 4; ++j)
                acc[i][j] = __builtin_amdgcn_mfma_f32_16x16x32_bf16(a[i], b[j], acc[i][j], 0, 0, 0);
        __syncthreads();
    }
#pragma unroll
    for (int i = 0; i < 4; ++i)
#pragma unroll
        for (int j = 0; j < 4; ++j)
#pragma unroll
            for (int r = 0; r < 4; ++r) {
                const int m = m0 + wm + (i << 4) + (lq << 2) + r;
                const int n = n0 + wn + (j << 4) + lr;
                C[(size_t)m * ldc + n] = f2b(acc[i][j][r] * scale);
            }
}

// ---------------------------------------------------------------------------
// cell_gate: grid 512 = (b in [0,64)) x (n0-tile in [0,8)), 256 threads.
// ---------------------------------------------------------------------------
__global__ __launch_bounds__(256) void cell_gate(
    const unsigned short* __restrict__ AA, const unsigned short* __restrict__ XhT,
    const unsigned short* __restrict__ Hb, const unsigned short* __restrict__ WT,
    const float* __restrict__ bias, const float* __restrict__ wx,
    const float* __restrict__ xin, int t,
    const unsigned short* __restrict__ XSgT, int xsrow,
    const unsigned short* __restrict__ Go, const float* __restrict__ H32,
    const float* __restrict__ prW, const float* __restrict__ prb,
    float* __restrict__ Sgo,
    unsigned short* __restrict__ Zb, unsigned short* __restrict__ ZhT,
    float* __restrict__ R, int dec, int goflag)
{
    __shared__ __align__(16) unsigned short As[256 * 32];   // 16 KB
    __shared__ __align__(16) unsigned short Bs[128 * 32];   // 8 KB
    __shared__ __align__(16) unsigned short Shs[256 * 72];  // 36 KB (72: 16B-aligned rows)
    __shared__ float SgoS[256];
    const int tid = threadIdx.x;
    const int b = blockIdx.x >> 3, n0 = (blockIdx.x & 7) << 7;
    const int w = tid >> 6, l = tid & 63;
    const int lr = l & 15, lq = l >> 4;
    const int arow = tid >> 2, ak = (tid & 3) << 3;

    // ---- Phase 1: Sh[256][64] ----
    {
        const int wm = w << 6;
        f32x4 acc[4][4] = {};
        for (int k0 = 0; k0 < 1024; k0 += 32) {
#pragma unroll
            for (int p = 0; p < 4; ++p) {
                const int row = arow + (p << 6);
                const int grow = (p < 2) ? (n0 + row) : (896 + n0 + row);
                GLOAD_LDS16(AA + (size_t)grow * 1024 + k0 + ak, &As[(row << 5) + ak]);
            }
            GLOAD_LDS16(XhT + (size_t)((b << 6) + arow) * 1024 + k0 + ak,
                        &Bs[(arow << 5) + ak]);
            __syncthreads();
            bf16x8 a[4], bb[4];
#pragma unroll
            for (int i = 0; i < 4; ++i)
                a[i] = *(const bf16x8*)&As[((wm + (i << 4) + lr) << 5) + (lq << 3)];
#pragma unroll
            for (int j = 0; j < 4; ++j)
                bb[j] = *(const bf16x8*)&Bs[(((j << 4) + lr) << 5) + (lq << 3)];
#pragma unroll
            for (int i = 0; i < 4; ++i)
#pragma unroll
                for (int j = 0; j < 4; ++j)
                    acc[i][j] = __builtin_amdgcn_mfma_f32_16x16x32_bf16(a[i], bb[j], acc[i][j], 0, 0, 0);
            __syncthreads();
        }
        // Sh -> LDS (bf16), plus analytic go-gather (decoder, t>=1 only)
#pragma unroll
        for (int i = 0; i < 4; ++i)
#pragma unroll
            for (int j = 0; j < 4; ++j)
#pragma unroll
                for (int r = 0; r < 4; ++r) {
                    const int m = wm + (i << 4) + (lq << 2) + r;
                    const int c = (j << 4) + lr;
                    Shs[m * 72 + c] = f2b(acc[i][j][r]);
                }
        if (dec) {
            float pw[4];
#pragma unroll
            for (int j = 0; j < 4; ++j) pw[j] = prW[(j << 4) + lr];
            const float pb0 = prb[0];
#pragma unroll
            for (int i = 0; i < 4; ++i)
#pragma unroll
                for (int r = 0; r < 4; ++r) {
                    float v = acc[i][0][r] * pw[0] + acc[i][1][r] * pw[1]
                            + acc[i][2][r] * pw[2] + acc[i][3][r] * pw[3];
                    v += __shfl_down(v, 8, 16);
                    v += __shfl_down(v, 4, 16);
                    v += __shfl_down(v, 2, 16);
                    v += __shfl_down(v, 1, 16);
                    if (lr == 0) {
                        const int m = wm + (i << 4) + (lq << 2) + r;
                        const int grow = (m < 128) ? (n0 + m) : (896 + n0 + m);
                        // t=0: GO token is zero -> A@go = 0 (goflag==0)
                        const float val = goflag
                            ? (v + pb0 * ((m < 128) ? 1.f : 2.f)) : 0.f;
                        Sgo[(size_t)grow * 64 + b] = val;
                        SgoS[m] = val;
                    }
                }
        }
    }

    // ---- Phase 2: zr = sigmoid([h | Sh0 | Sh1] @ W + bias + corr) ----
    const int wm2 = (w >> 1) << 6, wn2 = (w & 1) << 6;
    f32x4 acc2[4][4] = {};
    for (int kk0 = 0; kk0 < 192; kk0 += 32) {
#pragma unroll
        for (int p = 0; p < 2; ++p)
            GLOAD_LDS16(WT + (size_t)(arow + (p << 6)) * 192 + kk0 + ak,
                        &Bs[((arow + (p << 6)) << 5) + ak]);
        if (kk0 < 64) {
#pragma unroll
            for (int p = 0; p < 2; ++p)
                GLOAD_LDS16(Hb + ((size_t)(b << 10) + n0 + arow + (p << 6)) * 64 + kk0 + ak,
                            &As[((arow + (p << 6)) << 5) + ak]);
        }
        __syncthreads();
        bf16x8 a[4], bb[4];
        if (kk0 < 64) {
#pragma unroll
            for (int i = 0; i < 4; ++i)
                a[i] = *(const bf16x8*)&As[((wm2 + (i << 4) + lr) << 5) + (lq << 3)];
        } else {
            const int rowb = (kk0 >= 128) ? 128 : 0;
            const int c0 = kk0 & 63;
#pragma unroll
            for (int i = 0; i < 4; ++i)
                a[i] = *(const bf16x8*)&Shs[(rowb + wm2 + (i << 4) + lr) * 72 + c0 + (lq << 3)];
        }
#pragma unroll
        for (int j = 0; j < 4; ++j)
            bb[j] = *(const bf16x8*)&Bs[((wn2 + (j << 4) + lr) << 5) + (lq << 3)];
#pragma unroll
        for (int i = 0; i < 4; ++i)
#pragma unroll
            for (int j = 0; j < 4; ++j)
                acc2[i][j] = __builtin_amdgcn_mfma_f32_16x16x32_bf16(a[i], bb[j], acc2[i][j], 0, 0, 0);
        __syncthreads();
    }

#pragma unroll
    for (int i = 0; i < 4; ++i) {
        const int nb_loc = wm2 + (i << 4) + (lq << 2);      // local node 0..127
        const int node_base = n0 + nb_loc;
        float c0[4], c1[4], c2[4], c3[4], c4[4], c5[4];
        for (int r = 0; r < 4; ++r) {
            const int node = node_base + r;
            if (!dec) {
                c0[r] = xin[((b * 12 + t) << 10) + node];
                c1[r] = b2f(XSgT[(size_t)(xsrow + t * 64 + b) * 2048 + node]);
                c2[r] = b2f(XSgT[(size_t)(xsrow + t * 64 + b) * 2048 + 1024 + node]);
                c3[r] = c4[r] = c5[r] = 0.f;
            } else {
                c0[r] = b2f(Go[(b << 10) + node]);
                c1[r] = xin[((b * 12 + t) << 10) + node];
                c2[r] = SgoS[nb_loc + r];
                c3[r] = b2f(XSgT[(size_t)(xsrow + t * 64 + b) * 2048 + node]);
                c4[r] = SgoS[128 + nb_loc + r];
                c5[r] = b2f(XSgT[(size_t)(xsrow + t * 64 + b) * 2048 + 1024 + node]);
            }
        }
#pragma unroll
        for (int j = 0; j < 4; ++j) {
            const int jc = wn2 + (j << 4) + lr;
            const float bj = bias[jc];
            const float w0 = wx[jc], w1 = wx[128 + jc], w2 = wx[256 + jc];
            float w3 = 0.f, w4 = 0.f, w5 = 0.f;
            if (dec) { w3 = wx[384 + jc]; w4 = wx[512 + jc]; w5 = wx[640 + jc]; }
            if (jc < 64) {
                u16x4 pack;
                for (int r = 0; r < 4; ++r) {
                    float v = acc2[i][j][r] + bj + c0[r] * w0 + c1[r] * w1 + c2[r] * w2
                              + c3[r] * w3 + c4[r] * w4 + c5[r] * w5;
                    float g = 1.f / (1.f + __expf(-v));
                    const int node = node_base + r;
                    const size_t idx = ((size_t)(b << 10) + node) * 64 + jc;
                    float zh = g * H32[idx];
                    unsigned short zb = f2b(zh);
                    Zb[idx] = zb;
                    pack[r] = zb;
                }
                *(u16x4*)&ZhT[(size_t)((b << 6) + jc) * 1024 + node_base] = pack;
            } else {
                for (int r = 0; r < 4; ++r) {
                    float v = acc2[i][j][r] + bj + c0[r] * w0 + c1[r] * w1 + c2[r] * w2
                              + c3[r] * w3 + c4[r] * w4 + c5[r] * w5;
                    float g = 1.f / (1.f + __expf(-v));
                    const int node = node_base + r;
                    R[((size_t)(b << 10) + node) * 64 + (jc - 64)] = g;
                }
            }
        }
    }
}

// ---------------------------------------------------------------------------
// cell_update: grid 512 = (b, n0-tile), 256 threads.
// ---------------------------------------------------------------------------
__global__ __launch_bounds__(256) void cell_update(
    const unsigned short* __restrict__ AA, const unsigned short* __restrict__ ZhT,
    const unsigned short* __restrict__ Zb, const unsigned short* __restrict__ WT,
    const float* __restrict__ bias, const float* __restrict__ wx,
    const float* __restrict__ xin, int t,
    const unsigned short* __restrict__ XSgT, int xsrow,
    const float* __restrict__ Sgo, const float* __restrict__ Rg,
    float* __restrict__ H32, unsigned short* __restrict__ Hb,
    unsigned short* __restrict__ XhT,
    const float* __restrict__ prW, const float* __restrict__ prb,
    unsigned short* __restrict__ Go, float* __restrict__ outp, int dec)
{
    __shared__ __align__(16) unsigned short As[256 * 32];   // 16 KB
    __shared__ __align__(16) unsigned short Bs[64 * 32];    // 4 KB
    __shared__ __align__(16) unsigned short Shs[256 * 72];  // 36 KB
    const int tid = threadIdx.x;
    const int b = blockIdx.x >> 3, n0 = (blockIdx.x & 7) << 7;
    const int w = tid >> 6, l = tid & 63;
    const int lr = l & 15, lq = l >> 4;
    const int arow = tid >> 2, ak = (tid & 3) << 3;

    // ---- Phase 1: Sz[256][64] = AA @ ZhT[b-rows]^T ----
    {
        const int wm = w << 6;
        f32x4 acc[4][4] = {};
        for (int k0 = 0; k0 < 1024; k0 += 32) {
#pragma unroll
            for (int p = 0; p < 4; ++p) {
                const int row = arow + (p << 6);
                const int grow = (p < 2) ? (n0 + row) : (896 + n0 + row);
                GLOAD_LDS16(AA + (size_t)grow * 1024 + k0 + ak, &As[(row << 5) + ak]);
            }
            GLOAD_LDS16(ZhT + (size_t)((b << 6) + arow) * 1024 + k0 + ak,
                        &Bs[(arow << 5) + ak]);
            __syncthreads();
            bf16x8 a[4], bb[4];
#pragma unroll
            for (int i = 0; i < 4; ++i)
                a[i] = *(const bf16x8*)&As[((wm + (i << 4) + lr) << 5) + (lq << 3)];
#pragma unroll
            for (int j = 0; j < 4; ++j)
                bb[j] = *(const bf16x8*)&Bs[(((j << 4) + lr) << 5) + (lq << 3)];
#pragma unroll
            for (int i = 0; i < 4; ++i)
#pragma unroll
                for (int j = 0; j < 4; ++j)
                    acc[i][j] = __builtin_amdgcn_mfma_f32_16x16x32_bf16(a[i], bb[j], acc[i][j], 0, 0, 0);
            __syncthreads();
        }
#pragma unroll
        for (int i = 0; i < 4; ++i)
#pragma unroll
            for (int j = 0; j < 4; ++j)
#pragma unroll
                for (int r = 0; r < 4; ++r) {
                    const int m = wm + (i << 4) + (lq << 2) + r;
                    const int c = (j << 4) + lr;
                    Shs[m * 72 + c] = f2b(acc[i][j][r]);
                }
    }

    // ---- Phase 2: hc = tanh([zh | Sz0 | Sz1] @ Wu + bias + corr); h'=r h+(1-r)hc
    const int wm2 = w << 5;
    f32x4 acc2[2][4] = {};
    for (int kk0 = 0; kk0 < 192; kk0 += 32) {
        GLOAD_LDS16(WT + (size_t)arow * 192 + kk0 + ak, &Bs[(arow << 5) + ak]);
        if (kk0 < 64) {
#pragma unroll
            for (int p = 0; p < 2; ++p)
                GLOAD_LDS16(Zb + ((size_t)(b << 10) + n0 + arow + (p << 6)) * 64 + kk0 + ak,
                            &As[((arow + (p << 6)) << 5) + ak]);
        }
        __syncthreads();
        bf16x8 a[2], bb[4];
        if (kk0 < 64) {
#pragma unroll
            for (int i = 0; i < 2; ++i)
                a[i] = *(const bf16x8*)&As[((wm2 + (i << 4) + lr) << 5) + (lq << 3)];
        } else {
            const int rowb = (kk0 >= 128) ? 128 : 0;
            const int c0 = kk0 & 63;
#pragma unroll
            for (int i = 0; i < 2; ++i)
                a[i] = *(const bf16x8*)&Shs[(rowb + wm2 + (i << 4) + lr) * 72 + c0 + (lq << 3)];
        }
#pragma unroll
        for (int j = 0; j < 4; ++j)
            bb[j] = *(const bf16x8*)&Bs[(((j << 4) + lr) << 5) + (lq << 3)];
#pragma unroll
        for (int i = 0; i < 2; ++i)
#pragma unroll
            for (int j = 0; j < 4; ++j)
                acc2[i][j] = __builtin_amdgcn_mfma_f32_16x16x32_bf16(a[i], bb[j], acc2[i][j], 0, 0, 0);
        __syncthreads();
    }

    float pw[4];
    if (dec) {
#pragma unroll
        for (int j = 0; j < 4; ++j) pw[j] = prW[(j << 4) + lr];
    }

#pragma unroll
    for (int i = 0; i < 2; ++i) {
        const int node_base = n0 + wm2 + (i << 4) + (lq << 2);
        float c0[4], c1[4], c2[4], c3[4], c4[4], c5[4];
        for (int r = 0; r < 4; ++r) {
            const int node = node_base + r;
            if (!dec) {
                c0[r] = xin[((b * 12 + t) << 10) + node];
                c1[r] = b2f(XSgT[(size_t)(xsrow + t * 64 + b) * 2048 + node]);
                c2[r] = b2f(XSgT[(size_t)(xsrow + t * 64 + b) * 2048 + 1024 + node]);
                c3[r] = c4[r] = c5[r] = 0.f;
            } else {
                c0[r] = b2f(Go[(b << 10) + node]);
                c1[r] = xin[((b * 12 + t) << 10) + node];
                c2[r] = Sgo[(size_t)node * 64 + b];
                c3[r] = b2f(XSgT[(size_t)(xsrow + t * 64 + b) * 2048 + node]);
                c4[r] = Sgo[(size_t)(1024 + node) * 64 + b];
                c5[r] = b2f(XSgT[(size_t)(xsrow + t * 64 + b) * 2048 + 1024 + node]);
            }
        }
        float psum[4] = {0.f, 0.f, 0.f, 0.f};
#pragma unroll
        for (int j = 0; j < 4; ++j) {
            const int jc = (j << 4) + lr;
            const float bj = bias[jc];
            const float w0 = wx[jc], w1 = wx[64 + jc], w2 = wx[128 + jc];
            float w3 = 0.f, w4 = 0.f, w5 = 0.f;
            if (dec) { w3 = wx[192 + jc]; w4 = wx[256 + jc]; w5 = wx[320 + jc]; }
            u16x4 pack;
            for (int r = 0; r < 4; ++r) {
                float v = acc2[i][j][r] + bj + c0[r] * w0 + c1[r] * w1 + c2[r] * w2
                          + c3[r] * w3 + c4[r] * w4 + c5[r] * w5;
                float hc = tanhf(v);
                const int node = node_base + r;
                const size_t idx = ((size_t)(b << 10) + node) * 64 + jc;
                float rr = Rg[idx];
                float hn = rr * H32[idx] + (1.f - rr) * hc;
                H32[idx] = hn;
                unsigned short hb = f2b(hn);
                Hb[idx] = hb;
                pack[r] = hb;
                if (dec) psum[r] += hn * pw[j];
            }
            *(u16x4*)&XhT[(size_t)((b << 6) + jc) * 1024 + node_base] = pack;
        }
        if (dec) {
#pragma unroll
            for (int r = 0; r < 4; ++r) {
                float v = psum[r];
                v += __shfl_down(v, 8, 16);
                v += __shfl_down(v, 4, 16);
                v += __shfl_down(v, 2, 16);
                v += __shfl_down(v, 1, 16);
                if (lr == 0) {
                    const int node = node_base + r;
                    const float go = v + prb[0];
                    Go[(b << 10) + node] = f2b(go);
                    outp[((size_t)(b * 12 + t) << 10) + node] = go;
                }
            }
        }
    }
}

// ---------------------------------------------------------------------------
__global__ __launch_bounds__(256) void adj_softmax(
    const float* __restrict__ E, unsigned short* __restrict__ A)
{
    __shared__ float Es[8192];
    __shared__ float vals[1024];
    __shared__ float red[8];
    const int tid = threadIdx.x;
    const int r = blockIdx.x;
    for (int i = tid; i < 8192; i += 256) Es[i] = E[i];
    __syncthreads();
    float er[8];
#pragma unroll
    for (int e = 0; e < 8; ++e) er[e] = Es[(r << 3) + e];
    float lmax = -1e30f;
    for (int c = tid; c < 1024; c += 256) {
        float s = 0.f;
#pragma unroll
        for (int e = 0; e < 8; ++e) s += er[e] * Es[(c << 3) + e];
        s = fmaxf(s, 0.f);
        vals[c] = s;
        lmax = fmaxf(lmax, s);
    }
    for (int off = 32; off; off >>= 1) lmax = fmaxf(lmax, __shfl_down(lmax, off, 64));
    if ((tid & 63) == 0) red[tid >> 6] = lmax;
    __syncthreads();
    const float m = fmaxf(fmaxf(red[0], red[1]), fmaxf(red[2], red[3]));
    float lsum = 0.f;
    for (int c = tid; c < 1024; c += 256) {
        float e = __expf(vals[c] - m);
        vals[c] = e;
        lsum += e;
    }
    for (int off = 32; off; off >>= 1) lsum += __shfl_down(lsum, off, 64);
    if ((tid & 63) == 0) red[4 + (tid >> 6)] = lsum;
    __syncthreads();
    const float inv = 1.f / (red[4] + red[5] + red[6] + red[7]);
    for (int c = tid; c < 1024; c += 256)
        A[(r << 10) + c] = f2b(vals[c] * inv);
}

__global__ __launch_bounds__(256) void transpose_bf16(
    const unsigned short* __restrict__ src, unsigned short* __restrict__ dst)
{
    __shared__ unsigned short tile[64][65];
    const int bx = blockIdx.x & 15, by = blockIdx.x >> 4;
    const int x0 = bx << 6, y0 = by << 6;
    for (int i = threadIdx.x; i < 4096; i += 256) {
        const int r = i >> 6, c = i & 63;
        tile[r][c] = src[((y0 + r) << 10) + x0 + c];
    }
    __syncthreads();
    for (int i = threadIdx.x; i < 4096; i += 256) {
        const int r = i >> 6, c = i & 63;
        dst[((x0 + r) << 10) + y0 + c] = tile[c][r];
    }
}

__global__ __launch_bounds__(256) void build_xall(
    const float* __restrict__ x, const float* __restrict__ y,
    unsigned short* __restrict__ XallT)
{
    const int id = blockIdx.x * 256 + threadIdx.x;
    const int row = id >> 10, n = id & 1023;
    int t, b;
    const float* src;
    if (row < 768) { t = row >> 6; b = row & 63; src = x; }
    else { const int rr = row - 768; t = rr >> 6; b = rr & 63; src = y; }
    XallT[id] = f2b(src[((b * 12 + t) << 10) + n]);
}

__global__ __launch_bounds__(256) void wprep(
    const float* egW, const float* egb,
    const float* euW, const float* eub,
    const float* dgW, const float* dgb,
    const float* duW, const float* dub,
    const float* pW, const float* pb,
    unsigned short* WgTe, unsigned short* WuTe, unsigned short* WgTd, unsigned short* WuTd,
    float* wxge, float* wxue, float* wxgd, float* wxud,
    float* bge, float* bue, float* bgd, float* bud,
    float* projW, float* projb)
{
    const int tid0 = blockIdx.x * 256 + threadIdx.x;
    const int stride = 256 * gridDim.x;
    for (int i = tid0; i < 128 * 192; i += stride) {
        const int j = i / 192, kk = i % 192, k = kk >> 6, c = kk & 63;
        float v = egW[(k * 65 + 1 + c) * 128 + j];
        if (k == 0) v -= egW[(131 + c) * 128 + j];
        WgTe[i] = f2b(v);
    }
    for (int i = tid0; i < 64 * 192; i += stride) {
        const int j = i / 192, kk = i % 192, k = kk >> 6, c = kk & 63;
        float v = euW[(k * 65 + 1 + c) * 64 + j];
        if (k == 0) v -= euW[(131 + c) * 64 + j];
        WuTe[i] = f2b(v);
    }
    for (int i = tid0; i < 128 * 192; i += stride) {
        const int j = i / 192, kk = i % 192, k = kk >> 6, c = kk & 63;
        float v = dgW[(k * 66 + 2 + c) * 128 + j];
        if (k == 0) v -= dgW[(134 + c) * 128 + j];
        WgTd[i] = f2b(v);
    }
    for (int i = tid0; i < 64 * 192; i += stride) {
        const int j = i / 192, kk = i % 192, k = kk >> 6, c = kk & 63;
        float v = duW[(k * 66 + 2 + c) * 64 + j];
        if (k == 0) v -= duW[(134 + c) * 64 + j];
        WuTd[i] = f2b(v);
    }
    for (int i = tid0; i < 384; i += stride) {
        const int k = i >> 7, j = i & 127;
        float v;
        if (k == 0) v = egW[j] - egW[130 * 128 + j];
        else if (k == 1) v = egW[65 * 128 + j];
        else v = egW[130 * 128 + j];
        wxge[i] = v;
    }
    for (int i = tid0; i < 192; i += stride) {
        const int k = i >> 6, j = i & 63;
        float v;
        if (k == 0) v = euW[j] - euW[130 * 64 + j];
        else if (k == 1) v = euW[65 * 64 + j];
        else v = euW[130 * 64 + j];
        wxue[i] = v;
    }
    for (int i = tid0; i < 768; i += stride) {
        const int k = i >> 7, j = i & 127;
        float v;
        switch (k) {
            case 0: v = dgW[j] - dgW[132 * 128 + j]; break;
            case 1: v = dgW[128 + j] - dgW[133 * 128 + j]; break;
            case 2: v = dgW[66 * 128 + j]; break;
            case 3: v = dgW[67 * 128 + j]; break;
            case 4: v = dgW[132 * 128 + j]; break;
            default: v = dgW[133 * 128 + j]; break;
        }
        wxgd[i] = v;
    }
    for (int i = tid0; i < 384; i += stride) {
        const int k = i >> 6, j = i & 63;
        float v;
        switch (k) {
            case 0: v = duW[j] - duW[132 * 64 + j]; break;
            case 1: v = duW[64 + j] - duW[133 * 64 + j]; break;
            case 2: v = duW[66 * 64 + j]; break;
            case 3: v = duW[67 * 64 + j]; break;
            case 4: v = duW[132 * 64 + j]; break;
            default: v = duW[133 * 64 + j]; break;
        }
        wxud[i] = v;
    }
    for (int i = tid0; i < 128; i += stride) bge[i] = egb[i];
    for (int i = tid0; i < 64; i += stride) bue[i] = eub[i];
    for (int i = tid0; i < 128; i += stride) bgd[i] = dgb[i];
    for (int i = tid0; i < 64; i += stride) bud[i] = dub[i];
    for (int i = tid0; i < 64; i += stride) projW[i] = pW[i];
    if (tid0 == 0) projb[0] = pb[0];
}

// ---------------------------------------------------------------------------
extern "C" void kernel_launch(void* const* d_in, const int* in_sizes, int n_in,
                              void* d_out, int out_size, void* d_ws, size_t ws_size,
                              hipStream_t stream)
{
    (void)in_sizes; (void)n_in; (void)out_size; (void)ws_size;
    const float* x    = (const float*)d_in[0];
    const float* ycov = (const float*)d_in[1];
    const float* E    = (const float*)d_in[2];
    const float* egW  = (const float*)d_in[3];
    const float* egb  = (const float*)d_in[4];
    const float* euW  = (const float*)d_in[5];
    const float* eub  = (const float*)d_in[6];
    const float* dgW  = (const float*)d_in[7];
    const float* dgb  = (const float*)d_in[8];
    const float* duW  = (const float*)d_in[9];
    const float* dub  = (const float*)d_in[10];
    const float* pW   = (const float*)d_in[11];
    const float* pb   = (const float*)d_in[12];
    float* out = (float*)d_out;

    size_t off = 0;
    auto carve = [&](size_t bytes) -> void* {
        void* p = (char*)d_ws + off;
        off += (bytes + 255) & ~(size_t)255;
        return p;
    };
    unsigned short* AA    = (unsigned short*)carve(2048ull * 1024 * 2); // [A; 2A^2]
    unsigned short* XSgT  = (unsigned short*)carve(1536ull * 2048 * 2);
    unsigned short* XhT   = (unsigned short*)carve(4096ull * 1024 * 2);
    unsigned short* ZhT   = (unsigned short*)carve(4096ull * 1024 * 2);
    unsigned short* Hb    = (unsigned short*)carve(65536ull * 64 * 2);
    float*          H32   = (float*)carve(65536ull * 64 * 4);
    unsigned short* Zb    = (unsigned short*)carve(65536ull * 64 * 2);
    float*          R     = (float*)carve(65536ull * 64 * 4);
    float*          Sgo   = (float*)carve(2048ull * 64 * 4);
    unsigned short* Go    = (unsigned short*)carve(65536ull * 2);
    unsigned short* WgTe  = (unsigned short*)carve(128ull * 192 * 2);
    unsigned short* WuTe  = (unsigned short*)carve(64ull * 192 * 2);
    unsigned short* WgTd  = (unsigned short*)carve(128ull * 192 * 2);
    unsigned short* WuTd  = (unsigned short*)carve(64ull * 192 * 2);
    float* wxge = (float*)carve(384 * 4);
    float* wxue = (float*)carve(192 * 4);
    float* wxgd = (float*)carve(768 * 4);
    float* wxud = (float*)carve(384 * 4);
    float* bge  = (float*)carve(128 * 4);
    float* bue  = (float*)carve(64 * 4);
    float* bgd  = (float*)carve(128 * 4);
    float* bud  = (float*)carve(64 * 4);
    float* prW  = (float*)carve(64 * 4);
    float* prb  = (float*)carve(4);
    // Aliases: AT and XallT live inside Zb (both consumed before Zb's first write).
    unsigned short* AT    = Zb;
    unsigned short* XallT = Zb + 1024ull * 1024;

    hipMemsetAsync(XhT, 0, 4096ull * 1024 * 2, stream);
    hipMemsetAsync(Hb, 0, 65536ull * 64 * 2, stream);
    hipMemsetAsync(H32, 0, 65536ull * 64 * 4, stream);
    hipMemsetAsync(Go, 0, 65536ull * 2, stream);

    adj_softmax<<<1024, 256, 0, stream>>>(E, AA);
    transpose_bf16<<<256, 256, 0, stream>>>(AA, AT);
    gemm_bt<<<dim3(8, 8), 256, 0, stream>>>(AA, 1024, AT, 1024, AA + 1024 * 1024, 1024, 1024, 2.0f);
    build_xall<<<6144, 256, 0, stream>>>(x, ycov, XallT);
    gemm_bt<<<dim3(16, 12), 256, 0, stream>>>(XallT, 1024, AA, 1024, XSgT, 2048, 1024, 1.0f);
    wprep<<<64, 256, 0, stream>>>(egW, egb, euW, eub, dgW, dgb, duW, dub, pW, pb,
                                  WgTe, WuTe, WgTd, WuTd, wxge, wxue, wxgd, wxud,
                                  bge, bue, bgd, bud, prW, prb);

    for (int t = 0; t < 12; ++t) {  // encoder
        cell_gate<<<512, 256, 0, stream>>>(AA, XhT, Hb, WgTe, bge, wxge, x, t, XSgT, 0,
                                           Go, H32, prW, prb, Sgo, Zb, ZhT, R, 0, 0);
        cell_update<<<512, 256, 0, stream>>>(AA, ZhT, Zb, WuTe, bue, wxue, x, t, XSgT, 0,
                                             Sgo, R, H32, Hb, XhT, prW, prb, Go, out, 0);
    }
    for (int t = 0; t < 12; ++t) {  // decoder
        cell_gate<<<512, 256, 0, stream>>>(AA, XhT, Hb, WgTd, bgd, wxgd, ycov, t, XSgT, 768,
                                           Go, H32, prW, prb, Sgo, Zb, ZhT, R, 1, t > 0 ? 1 : 0);
        cell_update<<<512, 256, 0, stream>>>(AA, ZhT, Zb, WuTd, bud, wxud, ycov, t, XSgT, 768,
                                             Sgo, R, H32, Hb, XhT, prW, prb, Go, out, 1);
    }
}